// Round 14
// baseline (133.477 us; speedup 1.0000x reference)
//
#include <hip/hip_runtime.h>

typedef unsigned short u16;
typedef unsigned int u32;
typedef __attribute__((ext_vector_type(8))) short short8;   // 8 bf16 (4 VGPRs) - MFMA A/B frag
typedef __attribute__((ext_vector_type(4))) float f32x4;    // MFMA C/D frag
typedef __attribute__((ext_vector_type(4))) u32 u32x4;      // 16B move
typedef __attribute__((ext_vector_type(2))) u32 u32x2;      // 8B move
typedef __attribute__((ext_vector_type(4))) u16 u16x4;      // 8B move

#define AS1 __attribute__((address_space(1)))
#define AS3 __attribute__((address_space(3)))

constexpr int B_ = 2, N_ = 2048, H_ = 16;
constexpr int ROWS = B_ * N_;   // 4096
constexpr float LOG2E = 1.44269504088896f;

__device__ __forceinline__ float bf2f(u16 u){ union{u32 u; float f;} v; v.u = ((u32)u)<<16; return v.f; }
__device__ __forceinline__ u16 f2bf(float f){
  union{float f; u32 u;} v; v.f = f;
  u32 u = v.u; u += 0x7fffu + ((u>>16)&1u);   // RNE
  return (u16)(u>>16);
}
__device__ __forceinline__ u32 cvtpk(float lo, float hi){
  u32 r; asm("v_cvt_pk_bf16_f32 %0, %1, %2" : "=v"(r) : "v"(lo), "v"(hi)); return r;
}

// ---- fused setup: x->bf16 | trig table | Wq^T | Wo^T | [Wkv|Wkvh]^T  (one launch) ----
__global__ __launch_bounds__(256) void k_setup(const float* __restrict__ x, u16* __restrict__ xb,
                                               float2* __restrict__ tab,
                                               const float* __restrict__ Wq, const float* __restrict__ Wo,
                                               u16* __restrict__ WqT, u16* __restrict__ WoT,
                                               const float* __restrict__ Wkv, const float* __restrict__ Wkvh,
                                               u16* __restrict__ WkvT){
  __shared__ float T[64*65];
  int bid = blockIdx.x, tid = threadIdx.x;
  if (bid < 4096){                       // x conversion
    int i = (bid*256 + tid)*4;
    f32x4 v = *(const f32x4*)(x + i);
    u16x4 o; o[0]=f2bf(v[0]); o[1]=f2bf(v[1]); o[2]=f2bf(v[2]); o[3]=f2bf(v[3]);
    *(u16x4*)(xb + i) = o;
    return;
  }
  if (bid < 4352){                       // trig table
    int idx = (bid-4096)*256 + tid;
    int i = idx & 31, n = idx >> 5;
    float ang = (float)n * exp2f(-(float)i * 0.4152410118609203f);  // log2(10000)/32
    tab[idx] = make_float2(cosf(ang), sinf(ang));
    return;
  }
  if (bid < 4864){                       // Wq / Wo transpose (LDS-tiled)
    int m = (bid - 4352) >> 8;
    const float* in = m ? Wo : Wq;
    u16* out = m ? WoT : WqT;
    int t2 = (bid - 4352) & 255;
    int n0 = (t2 & 15) << 6, k0 = (t2 >> 4) << 6;
    #pragma unroll
    for (int s=0; s<4; ++s){
      int chunk = tid + s*256, r = chunk >> 4, c4 = (chunk & 15) << 2;
      *(f32x4*)(&T[r*65 + c4]) = *(const f32x4*)(&in[(size_t)(k0 + r)*1024 + n0 + c4]);
    }
    __syncthreads();
    #pragma unroll
    for (int s=0; s<2; ++s){
      int chunk = tid + s*256, d = chunk >> 3, c8 = (chunk & 7) << 3;
      u16x4 o1, o2;
      #pragma unroll
      for (int j=0; j<4; ++j){ o1[j] = f2bf(T[(c8+j)*65 + d]); o2[j] = f2bf(T[(c8+4+j)*65 + d]); }
      *(u16x4*)(&out[(size_t)(n0 + d)*1024 + k0 + c8])     = o1;
      *(u16x4*)(&out[(size_t)(n0 + d)*1024 + k0 + c8 + 4]) = o2;
    }
    return;
  }
  {                                      // WkvT build (768 blocks) -> rows 1024..1215 of WT
    int idx = (bid - 4864)*256 + tid;    // over 192*1024
    int n = idx >> 10, k = idx & 1023;
    float v = 0.f;
    if (n < 128)      v = Wkv[k*128 + n];
    else if (n < 160) v = Wkvh[k*32 + (n-128)];
    WkvT[idx] = f2bf(v);
  }
}

// ---- 128M x 64N GEMM, BK=64 (R10-proven). MODE1: N=1216 merged proj -> q(rope,bf16) + proj(fp32).
//      MODE0: plain fp32 out (out-projection). ----
template<int MODE>
__global__ __launch_bounds__(256) void k_gemm_mn(const u16* __restrict__ A, const u16* __restrict__ Bt,
                                                 void* __restrict__ Cv, float* __restrict__ proj,
                                                 const float2* __restrict__ tab,
                                                 int M, int N, int K){
  __shared__ u16 As[128*64];
  __shared__ u16 Bs[64*64];
  int ntile = N >> 6;
  int m0 = (blockIdx.x / ntile) << 7;
  int n0 = (blockIdx.x % ntile) << 6;
  int tid = threadIdx.x;
  int l = tid & 63, lr = l & 15, lc = l >> 4;
  int w = tid >> 6;
  int wm = w * 32;
  f32x4 acc[2][4] = {};
  for (int kt = 0; kt < K; kt += 64){
    __syncthreads();
    #pragma unroll
    for (int s = 0; s < 4; ++s){
      int chunk = tid + s*256, r = chunk >> 3, c8 = (chunk & 7) << 3;
      __builtin_amdgcn_global_load_lds(
        (const AS1 u32*)(&A[(size_t)(m0 + r)*K + kt + c8]),
        (AS3 u32*)(&As[r*64 + c8]), 16, 0, 0);
    }
    #pragma unroll
    for (int s = 0; s < 2; ++s){
      int chunk = tid + s*256, r = chunk >> 3, c8 = (chunk & 7) << 3;
      __builtin_amdgcn_global_load_lds(
        (const AS1 u32*)(&Bt[(size_t)(n0 + r)*K + kt + c8]),
        (AS3 u32*)(&Bs[r*64 + c8]), 16, 0, 0);
    }
    __syncthreads();
    short8 af[2][2], bfr[4][2];
    #pragma unroll
    for (int m=0; m<2; ++m)
      #pragma unroll
      for (int c=0; c<2; ++c)
        af[m][c] = *(const short8*)(&As[(wm + m*16 + lr)*64 + c*32 + lc*8]);
    #pragma unroll
    for (int n=0; n<4; ++n)
      #pragma unroll
      for (int c=0; c<2; ++c)
        bfr[n][c] = *(const short8*)(&Bs[(n*16 + lr)*64 + c*32 + lc*8]);
    __builtin_amdgcn_s_setprio(1);
    #pragma unroll
    for (int m=0; m<2; ++m)
      #pragma unroll
      for (int n=0; n<4; ++n)
        #pragma unroll
        for (int c=0; c<2; ++c)
          acc[m][n] = __builtin_amdgcn_mfma_f32_16x16x32_bf16(af[m][c], bfr[n][c], acc[m][n], 0,0,0);
    __builtin_amdgcn_s_setprio(0);
  }
  if constexpr (MODE == 0){
    float* C = (float*)Cv;
    #pragma unroll
    for (int m=0; m<2; ++m)
      #pragma unroll
      for (int n=0; n<4; ++n)
        #pragma unroll
        for (int r=0; r<4; ++r)
          C[(size_t)(m0 + wm + m*16 + lc*4 + r)*N + n0 + n*16 + lr] = acc[m][n][r];
  } else {
    if (n0 < 1024){
      // fused rope: this block's 64 cols = one head; pairs (i, i+32) = (acc[m][nf], acc[m][nf+2])
      u16* C = (u16*)Cv;
      #pragma unroll
      for (int m=0; m<2; ++m){
        int grow = m0 + wm + m*16 + lc*4;
        #pragma unroll
        for (int nf=0; nf<2; ++nf){
          int i = nf*16 + lr;
          #pragma unroll
          for (int r=0; r<4; ++r){
            float2 cs = tab[(size_t)((grow + r) & (N_-1))*32 + i];
            float x1 = acc[m][nf][r], x2 = acc[m][nf+2][r];
            C[(size_t)(grow + r)*1024 + n0 + i]      = f2bf(0.125f*(x1*cs.x - x2*cs.y));
            C[(size_t)(grow + r)*1024 + n0 + i + 32] = f2bf(0.125f*(x2*cs.x + x1*cs.y));
          }
        }
      }
    } else {
      int pc = n0 - 1024;   // KV projection columns -> proj fp32 (stride 192)
      #pragma unroll
      for (int m=0; m<2; ++m)
        #pragma unroll
        for (int n=0; n<4; ++n)
          #pragma unroll
          for (int r=0; r<4; ++r)
            proj[(size_t)(m0 + wm + m*16 + lc*4 + r)*192 + pc + n*16 + lr] = acc[m][n][r];
    }
  }
}

// ---- fused postproc: proj (ROWS x 192) -> k_rope bf16, gates (b,h,N) fp32, vt (b,64,N) bf16 ----
__global__ __launch_bounds__(256) void k_postproc2(const float* __restrict__ proj, const float2* __restrict__ tab,
                                                   u16* __restrict__ k_rope, float* __restrict__ k_head,
                                                   float* __restrict__ v_head, u16* __restrict__ vt){
  __shared__ u16 Tv[64*72];
  int n0 = blockIdx.x << 6;         // global row base (64 rows, never crosses b)
  int b = n0 >> 11;
  int tid = threadIdx.x;
  #pragma unroll
  for (int s=0; s<4; ++s){
    int chunk = tid + s*256, r = chunk >> 4, c4 = (chunk & 15) << 2;
    f32x4 v = *(const f32x4*)(&proj[(size_t)(n0+r)*192 + 64 + c4]);
    u16x4 o; o[0]=f2bf(v[0]); o[1]=f2bf(v[1]); o[2]=f2bf(v[2]); o[3]=f2bf(v[3]);
    *(u16x4*)(&Tv[r*72 + c4]) = o;
  }
  int wv = tid>>6, t = tid&63;
  for (int rr = wv; rr < 64; rr += 4){
    int row = n0 + rr, n = row & (N_-1);
    const float* p = proj + (size_t)row*192;
    if (t < 32){
      float hv = 1.f/(1.f + __expf(-p[128 + t]));
      if (t < 16) k_head[((size_t)b*16 + t)*N_ + n] = hv * LOG2E;   // log2e folded
      else        v_head[((size_t)b*16 + (t-16))*N_ + n] = hv;
      float2 cs = tab[n*32 + t];
      float k1 = p[t], k2 = p[32 + t];
      k_rope[(size_t)row*64 + t]      = f2bf(k1*cs.x - k2*cs.y);
      k_rope[(size_t)row*64 + 32 + t] = f2bf(k2*cs.x + k1*cs.y);
    }
  }
  __syncthreads();
  int nb = n0 & (N_-1);
  #pragma unroll
  for (int s=0; s<2; ++s){
    int chunk = tid + s*256, d = chunk>>3, c8 = (chunk&7)<<3;
    u32x4 o; u16* op = (u16*)&o;
    #pragma unroll
    for (int j=0; j<8; ++j) op[j] = Tv[(c8+j)*72 + d];
    *(u32x4*)(&vt[((size_t)b*64 + d)*N_ + nb + c8]) = o;
  }
}

// ---- flash attention v12: QT-PAIRED split-K — block covers q-tiles (p, 31-p) of one (b,h);
//      staging/barriers amortized over up to 2 tiles; split-K=3 over steps; static-shift softmax ----
__global__ __launch_bounds__(256, 4) void k_attn12(const u16* __restrict__ q_bf, const u16* __restrict__ k_rp,
                                                   const u16* __restrict__ vt, const float* __restrict__ k_hd,
                                                   const float* __restrict__ v_hd,
                                                   u16* __restrict__ o_part, float* __restrict__ l_part){
  __shared__ u16 Ks[64*72];        // [key][hd]
  __shared__ u16 Vts[64*72];       // [hd][key]
  __shared__ u16 Ps[4][16*72];     // per-wave P tile [q][k] (reused qb then qa; per-wave DS order)
  __shared__ float g_s[128];       // gk[0..63] | gv[0..63]
  int z = blockIdx.x;              // 0..1535, z = pidx*3 + sp
  int pidx = (int)((u32)z / 3u);
  int sp = z - pidx*3;
  int p = pidx & 15, h = (pidx >> 4) & 15, b = pidx >> 8;
  int qta = p, qtb = 31 - p;
  int nt = qtb + 1;                // 17..32 steps; total work 33 units (perfectly balanced)
  int t0 = (sp*nt)/3, t1 = ((sp+1)*nt)/3;   // never empty (nt>=17)
  int tid = threadIdx.x, w = tid>>6, l = tid&63, lr = l&15, lc = l>>4;
  size_t rowbase = (size_t)b*N_;
  size_t qoff_a = (rowbase + qta*64 + w*16 + lr)*1024 + h*64;
  size_t qoff_b = (rowbase + qtb*64 + w*16 + lr)*1024 + h*64;
  short8 qa0 = *(const short8*)(&q_bf[qoff_a + lc*8]);
  short8 qa1 = *(const short8*)(&q_bf[qoff_a + 32 + lc*8]);
  short8 qb0 = *(const short8*)(&q_bf[qoff_b + lc*8]);
  short8 qb1 = *(const short8*)(&q_bf[qoff_b + 32 + lc*8]);
  const float* gkp = k_hd + ((size_t)b*16 + h)*N_;
  const float* gvp = v_hd + ((size_t)b*16 + h)*N_;
  u32x4 kr[2], vr[2]; float gr;
  auto issue = [&](int t){
    int kg0 = t << 6;
    #pragma unroll
    for (int s=0; s<2; ++s){
      int chunk = tid + s*256, r = chunk>>3, c8 = (chunk&7)<<3;
      kr[s] = *(const u32x4*)(&k_rp[(rowbase + kg0 + r)*64 + c8]);
      vr[s] = *(const u32x4*)(&vt[((size_t)b*64 + r)*N_ + kg0 + c8]);
    }
    gr = (tid < 64) ? gkp[kg0 + tid] : ((tid < 128) ? gvp[kg0 + tid - 64] : 0.f);
  };
  float lsa = 0.f, lsb = 0.f;
  f32x4 oa[4] = {}, ob[4] = {};
  // one q-tile's step: QK^T -> gate -> mask(if diag) -> exp2 -> pack -> P-LDS -> PV
  auto process = [&](short8 q0, short8 q1, f32x4 (&o)[4], float& lsum, int qtt, int t, int kg0){
    f32x4 s4[4];
    __builtin_amdgcn_s_setprio(1);
    #pragma unroll
    for (int nf=0; nf<4; ++nf){
      short8 kf0 = *(const short8*)(&Ks[(nf*16+lr)*72 + lc*8]);
      short8 kf1 = *(const short8*)(&Ks[(nf*16+lr)*72 + 32 + lc*8]);
      f32x4 zz = {};
      zz = __builtin_amdgcn_mfma_f32_16x16x32_bf16(kf0, q0, zz, 0,0,0);
      s4[nf] = __builtin_amdgcn_mfma_f32_16x16x32_bf16(kf1, q1, zz, 0,0,0);
    }
    __builtin_amdgcn_s_setprio(0);
    #pragma unroll
    for (int nf=0; nf<4; ++nf){
      f32x4 gkv = *(const f32x4*)(&g_s[nf*16 + lc*4]);
      #pragma unroll
      for (int r=0; r<4; ++r) s4[nf][r] *= gkv[r];
    }
    if (t == qtt){
      int qg = qtt*64 + w*16 + lr;
      #pragma unroll
      for (int nf=0; nf<4; ++nf)
        #pragma unroll
        for (int r=0; r<4; ++r)
          if (kg0 + nf*16 + lc*4 + r > qg) s4[nf][r] = -1e30f;
    }
    #pragma unroll
    for (int nf=0; nf<4; ++nf)
      #pragma unroll
      for (int r=0; r<4; ++r){ s4[nf][r] = exp2f(s4[nf][r]); lsum += s4[nf][r]; }
    #pragma unroll
    for (int nf=0; nf<4; ++nf){
      f32x4 gvv = *(const f32x4*)(&g_s[64 + nf*16 + lc*4]);
      u32 lo = cvtpk(s4[nf][0]*gvv[0], s4[nf][1]*gvv[1]);
      u32 hi = cvtpk(s4[nf][2]*gvv[2], s4[nf][3]*gvv[3]);
      *(u32x2*)(&Ps[w][lr*72 + nf*16 + lc*4]) = (u32x2){lo, hi};
    }
    asm volatile("s_waitcnt lgkmcnt(0)" ::: "memory");
    __builtin_amdgcn_sched_barrier(0);
    short8 pf0 = *(const short8*)(&Ps[w][lr*72 + lc*8]);
    short8 pf1 = *(const short8*)(&Ps[w][lr*72 + 32 + lc*8]);
    __builtin_amdgcn_s_setprio(1);
    #pragma unroll
    for (int nf=0; nf<4; ++nf){
      short8 vf0 = *(const short8*)(&Vts[(nf*16+lr)*72 + lc*8]);
      short8 vf1 = *(const short8*)(&Vts[(nf*16+lr)*72 + 32 + lc*8]);
      o[nf] = __builtin_amdgcn_mfma_f32_16x16x32_bf16(pf0, vf0, o[nf], 0,0,0);
      o[nf] = __builtin_amdgcn_mfma_f32_16x16x32_bf16(pf1, vf1, o[nf], 0,0,0);
    }
    __builtin_amdgcn_s_setprio(0);
  };
  issue(t0);
  for (int t = t0; t < t1; ++t){
    int kg0 = t << 6;
    __syncthreads();                 // prior step's LDS reads done
    #pragma unroll
    for (int s=0; s<2; ++s){
      int chunk = tid + s*256, r = chunk>>3, c8 = (chunk&7)<<3;
      *(u32x4*)(&Ks[r*72 + c8])  = kr[s];
      *(u32x4*)(&Vts[r*72 + c8]) = vr[s];
    }
    if (tid < 128) g_s[tid] = gr;
    if (t + 1 < t1) issue(t+1);      // prefetch next tile (latency hides under compute)
    __syncthreads();                 // LDS ready
    process(qb0, qb1, ob, lsb, qtb, t, kg0);            // long tile: always active
    if (t <= qta) process(qa0, qa1, oa, lsa, qta, t, kg0);   // short tile: first qta+1 steps
  }
  // epilogue: reduce l per tile; write RAW partials (qa at offset 0, qb at 4096)
  lsa += __shfl_xor(lsa, 16); lsa += __shfl_xor(lsa, 32);
  lsb += __shfl_xor(lsb, 16); lsb += __shfl_xor(lsb, 32);
  if (lc == 0){
    l_part[z*128 + w*16 + lr]      = lsa;
    l_part[z*128 + 64 + w*16 + lr] = lsb;
  }
  u16* op = o_part + (size_t)z*8192;
  #pragma unroll
  for (int nf=0; nf<4; ++nf)
    #pragma unroll
    for (int r=0; r<4; ++r){
      op[(w*16 + lc*4 + r)*64 + nf*16 + lr]        = f2bf(oa[nf][r]);
      op[4096 + (w*16 + lc*4 + r)*64 + nf*16 + lr] = f2bf(ob[nf][r]);
    }
}

// ---- combine: attn_o[(b,q,h,d)] = (o0+o1+o2)/(l0+l1+l2), bf16 (paired-tile layout) ----
__global__ __launch_bounds__(256) void k_comb(const u16* __restrict__ o_part, const float* __restrict__ l_part,
                                              u16* __restrict__ attn_o){
  int z2 = blockIdx.x;             // 0..1023: h = z2&15, b = (z2>>4)&1, qt = z2>>5
  int h = z2 & 15, b = (z2 >> 4) & 1, qt = z2 >> 5;
  int p  = (qt < 16) ? qt : 31 - qt;
  int hs = (qt < 16) ? 0 : 1;      // qa = low tile, qb = high tile
  int pidx = (b << 8) | (h << 4) | p;
  size_t zb = (size_t)3*pidx;
  int tid = threadIdx.x;
  int q = tid >> 2, c16 = (tid & 3) << 4;
  size_t base0 = zb*8192 + (size_t)hs*4096 + q*64 + c16;
  float lv = l_part[zb*128 + hs*64 + q] + l_part[(zb+1)*128 + hs*64 + q] + l_part[(zb+2)*128 + hs*64 + q];
  float rl = __builtin_amdgcn_rcpf(lv);
  union U8 { u32x4 v; u16 s[8]; };
  U8 a0, a1, b0, b1, c0, c1, r0, r1;
  a0.v = *(const u32x4*)(o_part + base0);
  a1.v = *(const u32x4*)(o_part + base0 + 8);
  b0.v = *(const u32x4*)(o_part + base0 + 8192);
  b1.v = *(const u32x4*)(o_part + base0 + 8192 + 8);
  c0.v = *(const u32x4*)(o_part + base0 + 16384);
  c1.v = *(const u32x4*)(o_part + base0 + 16384 + 8);
  #pragma unroll
  for (int j=0; j<8; ++j){
    r0.s[j] = f2bf((bf2f(a0.s[j]) + bf2f(b0.s[j]) + bf2f(c0.s[j])) * rl);
    r1.s[j] = f2bf((bf2f(a1.s[j]) + bf2f(b1.s[j]) + bf2f(c1.s[j])) * rl);
  }
  u16* outp = attn_o + ((size_t)(b*N_ + qt*64 + q))*1024 + h*64 + c16;
  *(u32x4*)outp = r0.v;
  *(u32x4*)(outp + 8) = r1.v;
}

extern "C" void kernel_launch(void* const* d_in, const int* in_sizes, int n_in,
                              void* d_out, int out_size, void* d_ws, size_t ws_size,
                              hipStream_t stream){
  const float* x    = (const float*)d_in[0];
  const float* Wq   = (const float*)d_in[1];
  const float* Wkv  = (const float*)d_in[2];
  const float* Wkvh = (const float*)d_in[3];
  const float* Wo   = (const float*)d_in[4];
  float* out = (float*)d_out;

  char* p = (char*)d_ws;
  u16* xb      = (u16*)p;   p += (size_t)ROWS*1024*2;     // 8 MB (reused as attn_o later)
  u16* WT      = (u16*)p;   p += (size_t)1216*1024*2;     // 2.375 MB (WqT rows 0..1023, WkvT rows 1024..1215)
  u16* WoT     = (u16*)p;   p += (size_t)1024*1024*2;     // 2 MB
  float* proj  = (float*)p; p += (size_t)ROWS*192*4;      // 3 MB
  u16* q_bf    = (u16*)p;   p += (size_t)ROWS*1024*2;     // 8 MB
  u16* k_rp    = (u16*)p;   p += (size_t)ROWS*64*2;       // 512 KB
  u16* vt      = (u16*)p;   p += (size_t)B_*64*N_*2;      // 512 KB (b,64,N)
  float* k_hd  = (float*)p; p += (size_t)B_*H_*N_*4;      // 256 KB (b,h,N), log2e folded
  float* v_hd  = (float*)p; p += (size_t)B_*H_*N_*4;      // 256 KB (b,h,N)
  float2* tab  = (float2*)p; p += (size_t)N_*32*8;        // 512 KB rope trig
  u16* o_part  = (u16*)p;   p += (size_t)1536*8192*2;     // 25 MB split-k o partials (bf16, tile pairs)
  float* l_part= (float*)p; p += (size_t)1536*128*4;      // 768 KB split-k l partials
  u16* attn_o  = xb;  // xb dead after the projection GEMM

  k_setup<<<4096 + 256 + 512 + 768, 256, 0, stream>>>(x, xb, tab, Wq, Wo, WT, WoT,
                                                      Wkv, Wkvh, WT + (size_t)1024*1024);
  k_gemm_mn<1><<<(ROWS/128)*(1216/64), 256, 0, stream>>>(xb, WT, q_bf, proj, tab, ROWS, 1216, 1024);
  k_postproc2<<<ROWS/64, 256, 0, stream>>>(proj, tab, k_rp, k_hd, v_hd, vt);
  k_attn12<<<1536, 256, 0, stream>>>(q_bf, k_rp, vt, k_hd, v_hd, o_part, l_part);
  k_comb<<<1024, 256, 0, stream>>>(o_part, l_part, attn_o);
  k_gemm_mn<0><<<(ROWS/128)*(1024/64), 256, 0, stream>>>(attn_o, WoT, out, nullptr, nullptr, ROWS, 1024, 1024);
}

// Round 15
// 109.211 us; speedup vs baseline: 1.2222x; 1.2222x over previous
//
#include <hip/hip_runtime.h>

typedef unsigned short u16;
typedef unsigned int u32;
typedef __attribute__((ext_vector_type(8))) short short8;   // 8 bf16 (4 VGPRs) - MFMA A/B frag
typedef __attribute__((ext_vector_type(4))) float f32x4;    // MFMA C/D frag
typedef __attribute__((ext_vector_type(4))) u32 u32x4;      // 16B move
typedef __attribute__((ext_vector_type(2))) u32 u32x2;      // 8B move
typedef __attribute__((ext_vector_type(4))) u16 u16x4;      // 8B move

#define AS1 __attribute__((address_space(1)))
#define AS3 __attribute__((address_space(3)))

constexpr int B_ = 2, N_ = 2048, H_ = 16;
constexpr int ROWS = B_ * N_;   // 4096
constexpr float LOG2E = 1.44269504088896f;

__device__ __forceinline__ float bf2f(u16 u){ union{u32 u; float f;} v; v.u = ((u32)u)<<16; return v.f; }
__device__ __forceinline__ u16 f2bf(float f){
  union{float f; u32 u;} v; v.f = f;
  u32 u = v.u; u += 0x7fffu + ((u>>16)&1u);   // RNE
  return (u16)(u>>16);
}
__device__ __forceinline__ u32 cvtpk(float lo, float hi){
  u32 r; asm("v_cvt_pk_bf16_f32 %0, %1, %2" : "=v"(r) : "v"(lo), "v"(hi)); return r;
}

// ---- fused setup: x->bf16 | trig table | Wq^T | Wo^T | [Wkv|Wkvh]^T  (one launch) ----
__global__ __launch_bounds__(256) void k_setup(const float* __restrict__ x, u16* __restrict__ xb,
                                               float2* __restrict__ tab,
                                               const float* __restrict__ Wq, const float* __restrict__ Wo,
                                               u16* __restrict__ WqT, u16* __restrict__ WoT,
                                               const float* __restrict__ Wkv, const float* __restrict__ Wkvh,
                                               u16* __restrict__ WkvT){
  __shared__ float T[64*65];
  int bid = blockIdx.x, tid = threadIdx.x;
  if (bid < 4096){                       // x conversion
    int i = (bid*256 + tid)*4;
    f32x4 v = *(const f32x4*)(x + i);
    u16x4 o; o[0]=f2bf(v[0]); o[1]=f2bf(v[1]); o[2]=f2bf(v[2]); o[3]=f2bf(v[3]);
    *(u16x4*)(xb + i) = o;
    return;
  }
  if (bid < 4352){                       // trig table
    int idx = (bid-4096)*256 + tid;
    int i = idx & 31, n = idx >> 5;
    float ang = (float)n * exp2f(-(float)i * 0.4152410118609203f);  // log2(10000)/32
    tab[idx] = make_float2(cosf(ang), sinf(ang));
    return;
  }
  if (bid < 4864){                       // Wq / Wo transpose (LDS-tiled)
    int m = (bid - 4352) >> 8;
    const float* in = m ? Wo : Wq;
    u16* out = m ? WoT : WqT;
    int t2 = (bid - 4352) & 255;
    int n0 = (t2 & 15) << 6, k0 = (t2 >> 4) << 6;
    #pragma unroll
    for (int s=0; s<4; ++s){
      int chunk = tid + s*256, r = chunk >> 4, c4 = (chunk & 15) << 2;
      *(f32x4*)(&T[r*65 + c4]) = *(const f32x4*)(&in[(size_t)(k0 + r)*1024 + n0 + c4]);
    }
    __syncthreads();
    #pragma unroll
    for (int s=0; s<2; ++s){
      int chunk = tid + s*256, d = chunk >> 3, c8 = (chunk & 7) << 3;
      u16x4 o1, o2;
      #pragma unroll
      for (int j=0; j<4; ++j){ o1[j] = f2bf(T[(c8+j)*65 + d]); o2[j] = f2bf(T[(c8+4+j)*65 + d]); }
      *(u16x4*)(&out[(size_t)(n0 + d)*1024 + k0 + c8])     = o1;
      *(u16x4*)(&out[(size_t)(n0 + d)*1024 + k0 + c8 + 4]) = o2;
    }
    return;
  }
  {                                      // WkvT build (768 blocks) -> rows 1024..1215 of WT
    int idx = (bid - 4864)*256 + tid;    // over 192*1024
    int n = idx >> 10, k = idx & 1023;
    float v = 0.f;
    if (n < 128)      v = Wkv[k*128 + n];
    else if (n < 160) v = Wkvh[k*32 + (n-128)];
    WkvT[idx] = f2bf(v);
  }
}

// ---- 128M x 64N GEMM, BK=64 (R10-proven). MODE1: N=1216 merged proj -> q(rope,bf16) + proj(fp32).
//      MODE0: plain fp32 out (out-projection). ----
template<int MODE>
__global__ __launch_bounds__(256) void k_gemm_mn(const u16* __restrict__ A, const u16* __restrict__ Bt,
                                                 void* __restrict__ Cv, float* __restrict__ proj,
                                                 const float2* __restrict__ tab,
                                                 int M, int N, int K){
  __shared__ u16 As[128*64];
  __shared__ u16 Bs[64*64];
  int ntile = N >> 6;
  int m0 = (blockIdx.x / ntile) << 7;
  int n0 = (blockIdx.x % ntile) << 6;
  int tid = threadIdx.x;
  int l = tid & 63, lr = l & 15, lc = l >> 4;
  int w = tid >> 6;
  int wm = w * 32;
  f32x4 acc[2][4] = {};
  for (int kt = 0; kt < K; kt += 64){
    __syncthreads();
    #pragma unroll
    for (int s = 0; s < 4; ++s){
      int chunk = tid + s*256, r = chunk >> 3, c8 = (chunk & 7) << 3;
      __builtin_amdgcn_global_load_lds(
        (const AS1 u32*)(&A[(size_t)(m0 + r)*K + kt + c8]),
        (AS3 u32*)(&As[r*64 + c8]), 16, 0, 0);
    }
    #pragma unroll
    for (int s = 0; s < 2; ++s){
      int chunk = tid + s*256, r = chunk >> 3, c8 = (chunk & 7) << 3;
      __builtin_amdgcn_global_load_lds(
        (const AS1 u32*)(&Bt[(size_t)(n0 + r)*K + kt + c8]),
        (AS3 u32*)(&Bs[r*64 + c8]), 16, 0, 0);
    }
    __syncthreads();
    short8 af[2][2], bfr[4][2];
    #pragma unroll
    for (int m=0; m<2; ++m)
      #pragma unroll
      for (int c=0; c<2; ++c)
        af[m][c] = *(const short8*)(&As[(wm + m*16 + lr)*64 + c*32 + lc*8]);
    #pragma unroll
    for (int n=0; n<4; ++n)
      #pragma unroll
      for (int c=0; c<2; ++c)
        bfr[n][c] = *(const short8*)(&Bs[(n*16 + lr)*64 + c*32 + lc*8]);
    __builtin_amdgcn_s_setprio(1);
    #pragma unroll
    for (int m=0; m<2; ++m)
      #pragma unroll
      for (int n=0; n<4; ++n)
        #pragma unroll
        for (int c=0; c<2; ++c)
          acc[m][n] = __builtin_amdgcn_mfma_f32_16x16x32_bf16(af[m][c], bfr[n][c], acc[m][n], 0,0,0);
    __builtin_amdgcn_s_setprio(0);
  }
  if constexpr (MODE == 0){
    float* C = (float*)Cv;
    #pragma unroll
    for (int m=0; m<2; ++m)
      #pragma unroll
      for (int n=0; n<4; ++n)
        #pragma unroll
        for (int r=0; r<4; ++r)
          C[(size_t)(m0 + wm + m*16 + lc*4 + r)*N + n0 + n*16 + lr] = acc[m][n][r];
  } else {
    if (n0 < 1024){
      // fused rope: this block's 64 cols = one head; pairs (i, i+32) = (acc[m][nf], acc[m][nf+2])
      u16* C = (u16*)Cv;
      #pragma unroll
      for (int m=0; m<2; ++m){
        int grow = m0 + wm + m*16 + lc*4;
        #pragma unroll
        for (int nf=0; nf<2; ++nf){
          int i = nf*16 + lr;
          #pragma unroll
          for (int r=0; r<4; ++r){
            float2 cs = tab[(size_t)((grow + r) & (N_-1))*32 + i];
            float x1 = acc[m][nf][r], x2 = acc[m][nf+2][r];
            C[(size_t)(grow + r)*1024 + n0 + i]      = f2bf(0.125f*(x1*cs.x - x2*cs.y));
            C[(size_t)(grow + r)*1024 + n0 + i + 32] = f2bf(0.125f*(x2*cs.x + x1*cs.y));
          }
        }
      }
    } else {
      int pc = n0 - 1024;   // KV projection columns -> proj fp32 (stride 192)
      #pragma unroll
      for (int m=0; m<2; ++m)
        #pragma unroll
        for (int n=0; n<4; ++n)
          #pragma unroll
          for (int r=0; r<4; ++r)
            proj[(size_t)(m0 + wm + m*16 + lc*4 + r)*192 + pc + n*16 + lr] = acc[m][n][r];
    }
  }
}

// ---- fused postproc: proj (ROWS x 192) -> k_rope bf16, gates (b,h,N) fp32, vt (b,64,N) bf16 ----
__global__ __launch_bounds__(256) void k_postproc2(const float* __restrict__ proj, const float2* __restrict__ tab,
                                                   u16* __restrict__ k_rope, float* __restrict__ k_head,
                                                   float* __restrict__ v_head, u16* __restrict__ vt){
  __shared__ u16 Tv[64*72];
  int n0 = blockIdx.x << 6;         // global row base (64 rows, never crosses b)
  int b = n0 >> 11;
  int tid = threadIdx.x;
  #pragma unroll
  for (int s=0; s<4; ++s){
    int chunk = tid + s*256, r = chunk >> 4, c4 = (chunk & 15) << 2;
    f32x4 v = *(const f32x4*)(&proj[(size_t)(n0+r)*192 + 64 + c4]);
    u16x4 o; o[0]=f2bf(v[0]); o[1]=f2bf(v[1]); o[2]=f2bf(v[2]); o[3]=f2bf(v[3]);
    *(u16x4*)(&Tv[r*72 + c4]) = o;
  }
  int wv = tid>>6, t = tid&63;
  for (int rr = wv; rr < 64; rr += 4){
    int row = n0 + rr, n = row & (N_-1);
    const float* p = proj + (size_t)row*192;
    if (t < 32){
      float hv = 1.f/(1.f + __expf(-p[128 + t]));
      if (t < 16) k_head[((size_t)b*16 + t)*N_ + n] = hv * LOG2E;   // log2e folded
      else        v_head[((size_t)b*16 + (t-16))*N_ + n] = hv;
      float2 cs = tab[n*32 + t];
      float k1 = p[t], k2 = p[32 + t];
      k_rope[(size_t)row*64 + t]      = f2bf(k1*cs.x - k2*cs.y);
      k_rope[(size_t)row*64 + 32 + t] = f2bf(k2*cs.x + k1*cs.y);
    }
  }
  __syncthreads();
  int nb = n0 & (N_-1);
  #pragma unroll
  for (int s=0; s<2; ++s){
    int chunk = tid + s*256, d = chunk>>3, c8 = (chunk&7)<<3;
    u32x4 o; u16* op = (u16*)&o;
    #pragma unroll
    for (int j=0; j<8; ++j) op[j] = Tv[(c8+j)*72 + d];
    *(u32x4*)(&vt[((size_t)b*64 + d)*N_ + nb + c8]) = o;
  }
}

// ---- flash attention v13: NO P-ROUND-TRIP — k-dim of V permuted (sigma) so cvtpk words feed
//      PV MFMA directly as A-frags. LDS 18.9KB -> 8 blocks/CU. split-K=3, static-shift softmax ----
__global__ __launch_bounds__(256, 4) void k_attn13(const u16* __restrict__ q_bf, const u16* __restrict__ k_rp,
                                                   const u16* __restrict__ vt, const float* __restrict__ k_hd,
                                                   const float* __restrict__ v_hd,
                                                   u16* __restrict__ o_part, float* __restrict__ l_part){
  __shared__ u16 Ks[64*72];        // [key][hd]
  __shared__ u16 Vts[64*72];       // [hd][key-slot] — keys sigma-permuted per 32-key window
  __shared__ float g_s[128];       // gk[0..63] | gv[0..63]
  int z = blockIdx.x;              // 0..3071, z = pidx*3 + sp
  int pidx = (int)((u32)z / 3u);
  int sp = z - pidx*3;
  int qt = 31 - (pidx >> 5);       // LPT: longest q-tiles dispatch first
  int h = pidx & 15, b = (pidx >> 4) & 1;
  int nt = qt + 1;
  int t0 = (sp*nt)/3, t1 = ((sp+1)*nt)/3;
  int tid = threadIdx.x, w = tid>>6, l = tid&63, lr = l&15, lc = l>>4;
  if (t0 >= t1){                   // empty split: zero partials (non-overlapping, in-bounds)
    u16* op = o_part + (size_t)z*4096;
    for (int i = tid; i < 512; i += 256) *(u32x4*)(op + i*8) = (u32x4){0,0,0,0};
    if (tid < 64) l_part[z*64 + tid] = 0.f;
    return;
  }
  size_t rowbase = (size_t)b*N_;
  size_t qoff = (rowbase + qt*64 + w*16 + lr)*1024 + h*64;
  short8 qf0 = *(const short8*)(&q_bf[qoff + lc*8]);
  short8 qf1 = *(const short8*)(&q_bf[qoff + 32 + lc*8]);
  const float* gkp = k_hd + ((size_t)b*16 + h)*N_;
  const float* gvp = v_hd + ((size_t)b*16 + h)*N_;
  u32x4 kr[2], vr[2]; float gr;
  auto issue = [&](int t){
    int kg0 = t << 6;
    #pragma unroll
    for (int s=0; s<2; ++s){
      int chunk = tid + s*256, r = chunk>>3, c8 = (chunk&7)<<3;
      kr[s] = *(const u32x4*)(&k_rp[(rowbase + kg0 + r)*64 + c8]);
      vr[s] = *(const u32x4*)(&vt[((size_t)b*64 + r)*N_ + kg0 + c8]);
    }
    gr = (tid < 64) ? gkp[kg0 + tid] : ((tid < 128) ? gvp[kg0 + tid - 64] : 0.f);
  };
  float lsum = 0.f;
  f32x4 o[4] = {};
  issue(t0);
  for (int t = t0; t < t1; ++t){
    int kg0 = t << 6;
    __syncthreads();                 // prior compute's LDS reads done
    #pragma unroll
    for (int s=0; s<2; ++s){
      int chunk = tid + s*256, r = chunk>>3, c8 = (chunk&7)<<3;
      *(u32x4*)(&Ks[r*72 + c8]) = kr[s];
      // Vts: sigma-permuted key placement. 8-key chunk c8 -> two contiguous 4-key (8B) groups:
      //   window = c8>>5 (32-slot window base), c' = (c8&31)>>3, g0 = (c'&1)*16 + (c'>>1)*4
      //   keys +0..3 -> slots g0..g0+3, keys +4..7 -> slots g0+8..g0+11
      {
        int wbase = (c8 >> 5) << 5;
        int cp = (c8 & 31) >> 3;
        int g0 = (cp & 1)*16 + (cp >> 1)*4;
        u32x2 lov = { vr[s][0], vr[s][1] };
        u32x2 hiv = { vr[s][2], vr[s][3] };
        *(u32x2*)(&Vts[r*72 + wbase + g0])     = lov;
        *(u32x2*)(&Vts[r*72 + wbase + g0 + 8]) = hiv;
      }
    }
    if (tid < 128) g_s[tid] = gr;
    if (t + 1 < t1) issue(t+1);      // prefetch next tile (latency hides under compute)
    __syncthreads();                 // LDS ready
    // S^T = K * Q^T : lane (lr,lc) holds S[q=lr][k = kg0 + nf*16 + lc*4 + r]
    f32x4 s4[4];
    __builtin_amdgcn_s_setprio(1);
    #pragma unroll
    for (int nf=0; nf<4; ++nf){
      short8 kf0 = *(const short8*)(&Ks[(nf*16+lr)*72 + lc*8]);
      short8 kf1 = *(const short8*)(&Ks[(nf*16+lr)*72 + 32 + lc*8]);
      f32x4 zz = {};
      zz = __builtin_amdgcn_mfma_f32_16x16x32_bf16(kf0, qf0, zz, 0,0,0);
      s4[nf] = __builtin_amdgcn_mfma_f32_16x16x32_bf16(kf1, qf1, zz, 0,0,0);
    }
    __builtin_amdgcn_s_setprio(0);
    // gate (transient LDS reads), mask on diagonal, exp2 (static shift - scores bounded), local l
    #pragma unroll
    for (int nf=0; nf<4; ++nf){
      f32x4 gkv = *(const f32x4*)(&g_s[nf*16 + lc*4]);
      #pragma unroll
      for (int r=0; r<4; ++r) s4[nf][r] *= gkv[r];
    }
    if (t == qt){
      int qg = qt*64 + w*16 + lr;
      #pragma unroll
      for (int nf=0; nf<4; ++nf)
        #pragma unroll
        for (int r=0; r<4; ++r)
          if (kg0 + nf*16 + lc*4 + r > qg) s4[nf][r] = -1e30f;
    }
    #pragma unroll
    for (int nf=0; nf<4; ++nf)
      #pragma unroll
      for (int r=0; r<4; ++r){ s4[nf][r] = exp2f(s4[nf][r]); lsum += s4[nf][r]; }
    // fold v-gate, pack bf16 — packed words ARE the PV A-frags (V was sigma-permuted to match)
    u32 w0[4], w1[4];
    #pragma unroll
    for (int nf=0; nf<4; ++nf){
      f32x4 gvv = *(const f32x4*)(&g_s[64 + nf*16 + lc*4]);
      w0[nf] = cvtpk(s4[nf][0]*gvv[0], s4[nf][1]*gvv[1]);
      w1[nf] = cvtpk(s4[nf][2]*gvv[2], s4[nf][3]*gvv[3]);
    }
    union PF { u32x4 u; short8 s; } pf0, pf1;
    pf0.u = (u32x4){ w0[0], w1[0], w0[1], w1[1] };   // window 0: keys 0..31 (sigma order)
    pf1.u = (u32x4){ w0[2], w1[2], w0[3], w1[3] };   // window 1: keys 32..63
    __builtin_amdgcn_s_setprio(1);
    #pragma unroll
    for (int nf=0; nf<4; ++nf){
      short8 vf0 = *(const short8*)(&Vts[(nf*16+lr)*72 + lc*8]);
      short8 vf1 = *(const short8*)(&Vts[(nf*16+lr)*72 + 32 + lc*8]);
      o[nf] = __builtin_amdgcn_mfma_f32_16x16x32_bf16(pf0.s, vf0, o[nf], 0,0,0);
      o[nf] = __builtin_amdgcn_mfma_f32_16x16x32_bf16(pf1.s, vf1, o[nf], 0,0,0);
    }
    __builtin_amdgcn_s_setprio(0);
  }
  // epilogue: reduce l across lane-groups; write RAW partials (o bf16, l fp32)
  lsum += __shfl_xor(lsum, 16);
  lsum += __shfl_xor(lsum, 32);
  if (lc == 0) l_part[z*64 + w*16 + lr] = lsum;
  u16* op = o_part + (size_t)z*4096;
  #pragma unroll
  for (int nf=0; nf<4; ++nf)
    #pragma unroll
    for (int r=0; r<4; ++r)
      op[(w*16 + lc*4 + r)*64 + nf*16 + lr] = f2bf(o[nf][r]);
}

// ---- combine: attn_o[(b,q,h,d)] = (o0+o1+o2)/(l0+l1+l2), bf16 ----
__global__ __launch_bounds__(256) void k_comb(const u16* __restrict__ o_part, const float* __restrict__ l_part,
                                              u16* __restrict__ attn_o){
  int z2 = blockIdx.x;             // pidx: qt = 31-(z2>>5), h = z2&15, b = (z2>>4)&1
  int qt = 31 - (z2 >> 5), h = z2 & 15, b = (z2 >> 4) & 1;
  int tid = threadIdx.x;
  int q = tid >> 2, c16 = (tid & 3) << 4;
  size_t base0 = (size_t)(3*z2)*4096 + q*64 + c16;
  float lv = l_part[(3*z2)*64 + q] + l_part[(3*z2+1)*64 + q] + l_part[(3*z2+2)*64 + q];
  float rl = __builtin_amdgcn_rcpf(lv);
  union U8 { u32x4 v; u16 s[8]; };
  U8 a0, a1, b0, b1, c0, c1, r0, r1;
  a0.v = *(const u32x4*)(o_part + base0);
  a1.v = *(const u32x4*)(o_part + base0 + 8);
  b0.v = *(const u32x4*)(o_part + base0 + 4096);
  b1.v = *(const u32x4*)(o_part + base0 + 4096 + 8);
  c0.v = *(const u32x4*)(o_part + base0 + 8192);
  c1.v = *(const u32x4*)(o_part + base0 + 8192 + 8);
  #pragma unroll
  for (int j=0; j<8; ++j){
    r0.s[j] = f2bf((bf2f(a0.s[j]) + bf2f(b0.s[j]) + bf2f(c0.s[j])) * rl);
    r1.s[j] = f2bf((bf2f(a1.s[j]) + bf2f(b1.s[j]) + bf2f(c1.s[j])) * rl);
  }
  u16* outp = attn_o + ((size_t)(b*N_ + qt*64 + q))*1024 + h*64 + c16;
  *(u32x4*)outp = r0.v;
  *(u32x4*)(outp + 8) = r1.v;
}

extern "C" void kernel_launch(void* const* d_in, const int* in_sizes, int n_in,
                              void* d_out, int out_size, void* d_ws, size_t ws_size,
                              hipStream_t stream){
  const float* x    = (const float*)d_in[0];
  const float* Wq   = (const float*)d_in[1];
  const float* Wkv  = (const float*)d_in[2];
  const float* Wkvh = (const float*)d_in[3];
  const float* Wo   = (const float*)d_in[4];
  float* out = (float*)d_out;

  char* p = (char*)d_ws;
  u16* xb      = (u16*)p;   p += (size_t)ROWS*1024*2;     // 8 MB (reused as attn_o later)
  u16* WT      = (u16*)p;   p += (size_t)1216*1024*2;     // 2.375 MB (WqT rows 0..1023, WkvT rows 1024..1215)
  u16* WoT     = (u16*)p;   p += (size_t)1024*1024*2;     // 2 MB
  float* proj  = (float*)p; p += (size_t)ROWS*192*4;      // 3 MB
  u16* q_bf    = (u16*)p;   p += (size_t)ROWS*1024*2;     // 8 MB
  u16* k_rp    = (u16*)p;   p += (size_t)ROWS*64*2;       // 512 KB
  u16* vt      = (u16*)p;   p += (size_t)B_*64*N_*2;      // 512 KB (b,64,N)
  float* k_hd  = (float*)p; p += (size_t)B_*H_*N_*4;      // 256 KB (b,h,N), log2e folded
  float* v_hd  = (float*)p; p += (size_t)B_*H_*N_*4;      // 256 KB (b,h,N)
  float2* tab  = (float2*)p; p += (size_t)N_*32*8;        // 512 KB rope trig
  u16* o_part  = (u16*)p;   p += (size_t)3072*4096*2;     // 24 MB split-k o partials (bf16)
  float* l_part= (float*)p; p += (size_t)3072*64*4;       // 768 KB split-k l partials
  u16* attn_o  = xb;  // xb dead after the projection GEMM

  k_setup<<<4096 + 256 + 512 + 768, 256, 0, stream>>>(x, xb, tab, Wq, Wo, WT, WoT,
                                                      Wkv, Wkvh, WT + (size_t)1024*1024);
  k_gemm_mn<1><<<(ROWS/128)*(1216/64), 256, 0, stream>>>(xb, WT, q_bf, proj, tab, ROWS, 1216, 1024);
  k_postproc2<<<ROWS/64, 256, 0, stream>>>(proj, tab, k_rp, k_hd, v_hd, vt);
  k_attn13<<<3072, 256, 0, stream>>>(q_bf, k_rp, vt, k_hd, v_hd, o_part, l_part);
  k_comb<<<1024, 256, 0, stream>>>(o_part, l_part, attn_o);
  k_gemm_mn<0><<<(ROWS/128)*(1024/64), 256, 0, stream>>>(attn_o, WoT, out, nullptr, nullptr, ROWS, 1024, 1024);
}